// Round 2
// baseline (124.935 us; speedup 1.0000x reference)
//
#include <hip/hip_runtime.h>
#include <cstdint>
#include <cstddef>

#define B_  16
#define L_  8192
#define D_  256
#define H_  8
#define NB_ 8

// Workspace layout (floats)
static const long OFF_QK   = 0;                       // 8*256
static const long OFF_QB   = 2048;                    // 8
static const long OFF_SC   = 4096;                    // B*L*8 = 1048576 (holds exp(score))
static const long OFF_PART = 4096 + (long)B_ * L_ * 8;// partials [task][8][256], then pse [task][8]

// ---------------------------------------------------------------- kernel 1
// qk[h][e] = (sum_d q[h*32+d] * Wk[256+h*32+d][e]) / sqrt(32) ; qb[h] likewise with bk.
__global__ __launch_bounds__(256) void k_setup(const float* __restrict__ query,
                                               const float* __restrict__ W,
                                               const float* __restrict__ bias,
                                               float* __restrict__ ws) {
    __shared__ float q_s[256];
    int t = threadIdx.x;
    float acc = bias[t];
    const float* wr = W + (long)t * 256;
    for (int e = 0; e < 256; e += 4) {
        float4 qv = *(const float4*)(query + e);
        float4 wv = *(const float4*)(wr + e);
        acc += qv.x * wv.x + qv.y * wv.y + qv.z * wv.z + qv.w * wv.w;
    }
    q_s[t] = acc;
    __syncthreads();
    const float rs = 0.17677669529663687f; // 1/sqrt(32)
    for (int h = 0; h < 8; ++h) {
        float s = 0.f;
        #pragma unroll 8
        for (int d = 0; d < 32; ++d) {
            int r = 256 + h * 32 + d;
            s += q_s[h * 32 + d] * W[(long)r * 256 + t];
        }
        ws[OFF_QK + h * 256 + t] = s * rs;
    }
    if (t < 8) {
        float s = 0.f;
        for (int d = 0; d < 32; ++d) s += q_s[t * 32 + d] * bias[256 + t * 32 + d];
        ws[OFF_QB + t] = s * rs;
    }
}

// ---------------------------------------------------------------- kernel 2
// 3-step lane exchange over ep (low 3 lane bits): input p0..p7 = partial sums for h=0..7,
// output: full sum for h == ep.
__device__ __forceinline__ float reduce_ep(float p0, float p1, float p2, float p3,
                                           float p4, float p5, float p6, float p7, int ep) {
    bool b1 = (ep & 1) != 0;
    float s0 = b1 ? p0 : p1, k0 = b1 ? p1 : p0;
    float s1 = b1 ? p2 : p3, k1 = b1 ? p3 : p2;
    float s2 = b1 ? p4 : p5, k2 = b1 ? p5 : p4;
    float s3 = b1 ? p6 : p7, k3 = b1 ? p7 : p6;
    float n0 = k0 + __shfl_xor(s0, 1);
    float n1 = k1 + __shfl_xor(s1, 1);
    float n2 = k2 + __shfl_xor(s2, 1);
    float n3 = k3 + __shfl_xor(s3, 1);
    bool b2 = (ep & 2) != 0;
    float t0s = b2 ? n0 : n1, t0k = b2 ? n1 : n0;
    float t1s = b2 ? n2 : n3, t1k = b2 ? n3 : n2;
    float m0 = t0k + __shfl_xor(t0s, 2);
    float m1 = t1k + __shfl_xor(t1s, 2);
    bool b4 = (ep & 4) != 0;
    float us = b4 ? m0 : m1, uk = b4 ? m1 : m0;
    return uk + __shfl_xor(us, 4);
}

__device__ __forceinline__ float hsum4(float4 a) { return (a.x + a.y) + (a.z + a.w); }

// Each wave handles 16 tokens per iteration. lane = tk*8 + ep:
// tk = token within group (0..7, plus +8 for the second set), ep = e-slice {ep*4 + 32k}.
// Global loads: per instr, 8 rows x contiguous 128B -> fully coalesced.
// qk LDS loads: bank = 4*ep -> 8 banks, 8-way same-address broadcast -> conflict-free.
__global__ __launch_bounds__(256) void k_scores(const float* __restrict__ x,
                                                const float* __restrict__ ws,
                                                float* __restrict__ sc) {
    __shared__ float qk[2048];
    __shared__ float qb[8];
    int t = threadIdx.x;
    {
        const float4* src = (const float4*)(ws + OFF_QK);
        float4* dst = (float4*)qk;
        for (int i = t; i < 512; i += 256) dst[i] = src[i];
        if (t < 8) qb[t] = ws[OFF_QB + t];
    }
    __syncthreads();
    int lane = t & 63;
    int widx = t >> 6;
    int tk = lane >> 3, ep = lane & 7;
    int ep4 = ep * 4;
    int waveId = blockIdx.x * 4 + widx;
    int nWaves = gridDim.x * 4;
    for (int g = waveId; g < B_ * (L_ / 16); g += nWaves) {
        int b = g >> 9;               // 512 groups per batch
        int tok0 = (g & 511) << 4;
        const float* xb = x + ((long)b * L_ + tok0) * D_;
        float4 a0[8], a1[8];
        #pragma unroll
        for (int h = 0; h < 8; ++h) {
            a0[h] = make_float4(0.f, 0.f, 0.f, 0.f);
            a1[h] = make_float4(0.f, 0.f, 0.f, 0.f);
        }
        #pragma unroll
        for (int k = 0; k < 8; ++k) {
            float4 qv[8];
            #pragma unroll
            for (int h = 0; h < 8; ++h)
                qv[h] = *(const float4*)(qk + h * 256 + ep4 + 32 * k);
            float4 xv0 = *(const float4*)(xb + (long)tk * D_ + ep4 + 32 * k);
            float4 xv1 = *(const float4*)(xb + (long)(tk + 8) * D_ + ep4 + 32 * k);
            #pragma unroll
            for (int h = 0; h < 8; ++h) {
                a0[h].x += xv0.x * qv[h].x; a0[h].y += xv0.y * qv[h].y;
                a0[h].z += xv0.z * qv[h].z; a0[h].w += xv0.w * qv[h].w;
                a1[h].x += xv1.x * qv[h].x; a1[h].y += xv1.y * qv[h].y;
                a1[h].z += xv1.z * qv[h].z; a1[h].w += xv1.w * qv[h].w;
            }
        }
        {
            float tot = reduce_ep(hsum4(a0[0]), hsum4(a0[1]), hsum4(a0[2]), hsum4(a0[3]),
                                  hsum4(a0[4]), hsum4(a0[5]), hsum4(a0[6]), hsum4(a0[7]), ep);
            tot += qb[ep];
            sc[((long)b * L_ + tok0 + tk) * 8 + ep] = expf(tot);
        }
        {
            float tot = reduce_ep(hsum4(a1[0]), hsum4(a1[1]), hsum4(a1[2]), hsum4(a1[3]),
                                  hsum4(a1[4]), hsum4(a1[5]), hsum4(a1[6]), hsum4(a1[7]), ep);
            tot += qb[ep];
            sc[((long)b * L_ + tok0 + tk + 8) * 8 + ep] = expf(tot);
        }
    }
}

// ---------------------------------------------------------------- kernel 3
// One wave per (b, n, subchunk). Backend n is fixed per task -> register accumulators.
// Writes per-task partials; reduced deterministically in k_epi. No atomics anywhere.
//
// Mask dtype is detected at runtime: the harness may materialize the reference's
// bool mask as either 1-byte bools or int32. Reading the first 64 words as int32:
// packed bool bytes yield some word > 1 with overwhelming probability (random 0/1
// bytes: P(all 64 words <= 1) = 8^-64), while a genuine int32 0/1 mask never does.
template <int NSUB>
__global__ __launch_bounds__(256) void k_pool(const float* __restrict__ x,
                                              const unsigned char* __restrict__ mask,
                                              const int* __restrict__ bid,
                                              const float* __restrict__ sc,
                                              float* __restrict__ part,
                                              float* __restrict__ pse) {
    const int SUBLEN = L_ / NSUB;
    int widx = threadIdx.x >> 6, lane = threadIdx.x & 63;
    int task = blockIdx.x * 4 + widx;
    int b = task / (NB_ * NSUB);
    int n = (task / NSUB) & (NB_ - 1);
    int sub = task & (NSUB - 1);
    int l0 = sub * SUBLEN;
    const float* xb = x + (long)b * L_ * D_;
    const float* scb = sc + (long)b * L_ * 8;
    const int* bb = bid + (long)b * L_;

    // --- mask dtype detection (wave-uniform) ---
    const int* mi = (const int*)mask;
    unsigned v0 = (unsigned)mi[lane];
    bool bytemode = __ballot(v0 > 1u) != 0ull;
    const unsigned char* mb_byte = mask + (long)b * L_;
    const int* mb_int = mi + (long)b * L_;

    float4 acc[8];
    #pragma unroll
    for (int h = 0; h < 8; ++h) acc[h] = make_float4(0.f, 0.f, 0.f, 0.f);
    float se0 = 0.f, se1 = 0.f, se2 = 0.f, se3 = 0.f, se4 = 0.f, se5 = 0.f, se6 = 0.f, se7 = 0.f;
    for (int w0 = l0; w0 < l0 + SUBLEN; w0 += 64) {
        int l = w0 + lane;
        bool valid = bytemode ? (mb_byte[l] != 0) : (mb_int[l] != 0);
        bool m = valid && (bb[l] == n);
        unsigned long long bal = __ballot(m);
        while (bal) {
            int i = __ffsll(bal) - 1;
            bal &= bal - 1;
            int tok = w0 + i;
            const float* srow = scb + (long)tok * 8;
            float4 wA = *(const float4*)(srow);
            float4 wB = *(const float4*)(srow + 4);
            float4 xv = ((const float4*)(xb + (long)tok * D_))[lane];
            acc[0].x += wA.x * xv.x; acc[0].y += wA.x * xv.y; acc[0].z += wA.x * xv.z; acc[0].w += wA.x * xv.w;
            acc[1].x += wA.y * xv.x; acc[1].y += wA.y * xv.y; acc[1].z += wA.y * xv.z; acc[1].w += wA.y * xv.w;
            acc[2].x += wA.z * xv.x; acc[2].y += wA.z * xv.y; acc[2].z += wA.z * xv.z; acc[2].w += wA.z * xv.w;
            acc[3].x += wA.w * xv.x; acc[3].y += wA.w * xv.y; acc[3].z += wA.w * xv.z; acc[3].w += wA.w * xv.w;
            acc[4].x += wB.x * xv.x; acc[4].y += wB.x * xv.y; acc[4].z += wB.x * xv.z; acc[4].w += wB.x * xv.w;
            acc[5].x += wB.y * xv.x; acc[5].y += wB.y * xv.y; acc[5].z += wB.y * xv.z; acc[5].w += wB.y * xv.w;
            acc[6].x += wB.z * xv.x; acc[6].y += wB.z * xv.y; acc[6].z += wB.z * xv.z; acc[6].w += wB.z * xv.w;
            acc[7].x += wB.w * xv.x; acc[7].y += wB.w * xv.y; acc[7].z += wB.w * xv.z; acc[7].w += wB.w * xv.w;
            se0 += wA.x; se1 += wA.y; se2 += wA.z; se3 += wA.w;
            se4 += wB.x; se5 += wB.y; se6 += wB.z; se7 += wB.w;
        }
    }
    long base = (long)task * 2048;
    #pragma unroll
    for (int h = 0; h < 8; ++h)
        *(float4*)(part + base + h * 256 + lane * 4) = acc[h];
    if (lane == 0) {
        float* p = pse + (long)task * 8;
        p[0] = se0; p[1] = se1; p[2] = se2; p[3] = se3;
        p[4] = se4; p[5] = se5; p[6] = se6; p[7] = se7;
    }
}

// ---------------------------------------------------------------- kernel 4
// One block per (n,b): reduce partials (fixed order), normalize, wv-project,
// out-project, LayerNorm, zero empty backends, write out[b][n][:].
template <int NSUB>
__global__ __launch_bounds__(256) void k_epi(const float* __restrict__ part,
                                             const float* __restrict__ pse,
                                             const float* __restrict__ W,
                                             const float* __restrict__ ib,
                                             const float* __restrict__ Wo,
                                             const float* __restrict__ ob,
                                             const float* __restrict__ gamma,
                                             const float* __restrict__ beta,
                                             float* __restrict__ out) {
    __shared__ float pn[2048];
    __shared__ float ses[8];
    __shared__ float ctx_s[256];
    __shared__ float r1[4], r2[4];
    int n = blockIdx.x & 7, b = blockIdx.x >> 3;
    int t = threadIdx.x;
    int tbase = b * (NB_ * NSUB) + n * NSUB;
    if (t < 8) {
        float s = 0.f;
        for (int sub = 0; sub < NSUB; ++sub) s += pse[(long)(tbase + sub) * 8 + t];
        ses[t] = s;
    }
    __syncthreads();
    bool has = ses[0] > 0.f;
    for (int j = 0; j < 8; ++j) {
        int idx = j * 256 + t;
        int h = idx >> 8;
        float s = 0.f;
        for (int sub = 0; sub < NSUB; ++sub) s += part[(long)(tbase + sub) * 2048 + idx];
        pn[idx] = has ? s / ses[h] : 0.f;
    }
    __syncthreads();
    // ctx[t] = bv[t] + sum_e pn[h][e] * Wv[512+t][e]
    int h = t >> 5;
    float c = ib[512 + t];
    {
        const float* wr = W + (long)(512 + t) * 256;
        const float* ph = pn + h * 256;
        for (int e = 0; e < 256; e += 4) {
            float4 wv4 = *(const float4*)(wr + e);
            float4 pv4 = *(const float4*)(ph + e);
            c += wv4.x * pv4.x + wv4.y * pv4.y + wv4.z * pv4.z + wv4.w * pv4.w;
        }
    }
    ctx_s[t] = c;
    __syncthreads();
    float o = ob[t];
    {
        const float* wr = Wo + (long)t * 256;
        for (int d = 0; d < 256; d += 4) {
            float4 wv4 = *(const float4*)(wr + d);
            float4 cv4 = *(const float4*)(ctx_s + d);
            o += wv4.x * cv4.x + wv4.y * cv4.y + wv4.z * cv4.z + wv4.w * cv4.w;
        }
    }
    // LayerNorm over 256
    float s1 = o, s2 = o * o;
    #pragma unroll
    for (int off = 32; off >= 1; off >>= 1) {
        s1 += __shfl_down(s1, off);
        s2 += __shfl_down(s2, off);
    }
    if ((t & 63) == 0) { r1[t >> 6] = s1; r2[t >> 6] = s2; }
    __syncthreads();
    float S1 = r1[0] + r1[1] + r1[2] + r1[3];
    float S2 = r2[0] + r2[1] + r2[2] + r2[3];
    float mu = S1 * (1.f / 256.f);
    float var = S2 * (1.f / 256.f) - mu * mu;
    float rr = rsqrtf(var + 1e-5f);
    float res = ((o - mu) * rr * gamma[t] + beta[t]) * (has ? 1.f : 0.f);
    out[((long)b * 8 + n) * 256 + t] = res;
}

// ---------------------------------------------------------------- launch
extern "C" void kernel_launch(void* const* d_in, const int* in_sizes, int n_in,
                              void* d_out, int out_size, void* d_ws, size_t ws_size,
                              hipStream_t stream) {
    const float* x     = (const float*)d_in[0];
    const float* query = (const float*)d_in[1];
    const float* W     = (const float*)d_in[2];
    const float* ib    = (const float*)d_in[3];
    const float* Wo    = (const float*)d_in[4];
    const float* ob    = (const float*)d_in[5];
    const float* gamma = (const float*)d_in[6];
    const float* beta  = (const float*)d_in[7];
    const unsigned char* mask = (const unsigned char*)d_in[8];
    const int* bid     = (const int*)d_in[9];
    float* out = (float*)d_out;
    float* ws  = (float*)d_ws;

    float* sc = ws + OFF_SC;

    k_setup<<<1, 256, 0, stream>>>(query, W, ib, ws);
    k_scores<<<1024, 256, 0, stream>>>(x, ws, sc);

    // Choose partial-buffer granularity by available workspace (no silent overflow).
    auto need = [](long nsub) {
        return (size_t)(OFF_PART + (long)B_ * NB_ * nsub * (2048 + 8)) * sizeof(float);
    };
    float* part = ws + OFF_PART;
    if (ws_size >= need(16)) {
        const int NSUB = 16; // 2048 wave-tasks
        float* pse = part + (long)B_ * NB_ * NSUB * 2048;
        k_pool<NSUB><<<(B_ * NB_ * NSUB) / 4, 256, 0, stream>>>(x, mask, bid, sc, part, pse);
        k_epi<NSUB><<<B_ * NB_, 256, 0, stream>>>(part, pse, W, ib, Wo, ob, gamma, beta, out);
    } else if (ws_size >= need(4)) {
        const int NSUB = 4; // 512 wave-tasks
        float* pse = part + (long)B_ * NB_ * NSUB * 2048;
        k_pool<NSUB><<<(B_ * NB_ * NSUB) / 4, 256, 0, stream>>>(x, mask, bid, sc, part, pse);
        k_epi<NSUB><<<B_ * NB_, 256, 0, stream>>>(part, pse, W, ib, Wo, ob, gamma, beta, out);
    } else {
        const int NSUB = 1; // 128 wave-tasks, minimal footprint
        float* pse = part + (long)B_ * NB_ * NSUB * 2048;
        k_pool<NSUB><<<(B_ * NB_ * NSUB) / 4, 256, 0, stream>>>(x, mask, bid, sc, part, pse);
        k_epi<NSUB><<<B_ * NB_, 256, 0, stream>>>(part, pse, W, ib, Wo, ob, gamma, beta, out);
    }
}

// Round 3
// 78.127 us; speedup vs baseline: 1.5991x; 1.5991x over previous
//
#include <hip/hip_runtime.h>
#include <cstdint>
#include <cstddef>

#define B_  16
#define L_  8192
#define D_  256
#define H_  8
#define NB_ 8

// Workspace layout (floats): qk[8][256], qb[8], then partials + pse.
static const long OFF_QK   = 0;     // 8*256
static const long OFF_QB   = 2048;  // 8
static const long OFF_PART = 4096;  // part[task][8][256] then pse[task][8]

// ---------------------------------------------------------------- kernel 1
// qk[h][e] = (sum_d q[h*32+d] * Wk[256+h*32+d][e]) / sqrt(32) ; qb[h] likewise with bk.
__global__ __launch_bounds__(256) void k_setup(const float* __restrict__ query,
                                               const float* __restrict__ W,
                                               const float* __restrict__ bias,
                                               float* __restrict__ ws) {
    __shared__ float q_s[256];
    int t = threadIdx.x;
    float acc = bias[t];
    const float* wr = W + (long)t * 256;
    for (int e = 0; e < 256; e += 4) {
        float4 qv = *(const float4*)(query + e);
        float4 wv = *(const float4*)(wr + e);
        acc += qv.x * wv.x + qv.y * wv.y + qv.z * wv.z + qv.w * wv.w;
    }
    q_s[t] = acc;
    __syncthreads();
    const float rs = 0.17677669529663687f; // 1/sqrt(32)
    for (int h = 0; h < 8; ++h) {
        float s = 0.f;
        #pragma unroll 8
        for (int d = 0; d < 32; ++d) {
            int r = 256 + h * 32 + d;
            s += q_s[h * 32 + d] * W[(long)r * 256 + t];
        }
        ws[OFF_QK + h * 256 + t] = s * rs;
    }
    if (t < 8) {
        float s = 0.f;
        for (int d = 0; d < 32; ++d) s += q_s[t * 32 + d] * bias[256 + t * 32 + d];
        ws[OFF_QB + t] = s * rs;
    }
}

// 3-step butterfly over the low 3 lane bits: p0..p7 = per-lane partials for h=0..7.
// Result: lane (g,ep) holds sum over its 8-lane octet of p[ep].
__device__ __forceinline__ float reduce_ep(float p0, float p1, float p2, float p3,
                                           float p4, float p5, float p6, float p7, int ep) {
    bool b1 = (ep & 1) != 0;
    float s0 = b1 ? p0 : p1, k0 = b1 ? p1 : p0;
    float s1 = b1 ? p2 : p3, k1 = b1 ? p3 : p2;
    float s2 = b1 ? p4 : p5, k2 = b1 ? p5 : p4;
    float s3 = b1 ? p6 : p7, k3 = b1 ? p7 : p6;
    float n0 = k0 + __shfl_xor(s0, 1);
    float n1 = k1 + __shfl_xor(s1, 1);
    float n2 = k2 + __shfl_xor(s2, 1);
    float n3 = k3 + __shfl_xor(s3, 1);
    bool b2 = (ep & 2) != 0;
    float t0s = b2 ? n0 : n1, t0k = b2 ? n1 : n0;
    float t1s = b2 ? n2 : n3, t1k = b2 ? n3 : n2;
    float m0 = t0k + __shfl_xor(t0s, 2);
    float m1 = t1k + __shfl_xor(t1s, 2);
    bool b4 = (ep & 4) != 0;
    float us = b4 ? m0 : m1, uk = b4 ? m1 : m0;
    return uk + __shfl_xor(us, 4);
}

// ---------------------------------------------------------------- kernel 2 (fused scores+pool)
// One block per (b, n, chunk). Each of the 4 waves scans a quarter of the chunk:
// ballot-screen mask&bid, gather matching rows (full 1 KiB row across 64 lanes),
// compute the 8 head scores in-register (qk fragment per lane), exp, accumulate
// weighted row into register acc. Cross-wave LDS reduction -> one partial per block.
// No atomics; deterministic order.
//
// Mask dtype detected at runtime (harness may give bool bytes or int32): packed
// 0/1 bytes read as int32 give some word > 1 with probability 1-8^-64.
template <int NCH>
__global__ __launch_bounds__(256, 4) void k_pool(const float* __restrict__ x,
                                                 const unsigned char* __restrict__ mask,
                                                 const int* __restrict__ bid,
                                                 const float* __restrict__ ws,
                                                 float* __restrict__ part,
                                                 float* __restrict__ pse) {
    const int CH = L_ / NCH;      // tokens per block
    const int WLEN = CH / 4;      // tokens per wave
    __shared__ float red[4 * 2048];
    __shared__ float rse[4 * 8];

    int t = threadIdx.x;
    int widx = t >> 6, lane = t & 63;
    int ep = lane & 7;

    int blk = blockIdx.x;
    int b  = blk / (NB_ * NCH);
    int n  = (blk / NCH) % NB_;
    int ch = blk % NCH;

    const float* xb  = x + (long)b * L_ * D_;
    const int*   bb  = bid + (long)b * L_;

    // qk fragment for this lane: qk[h][lane*4 .. lane*4+4), h=0..7  (32 VGPR)
    float4 qk0 = *(const float4*)(ws + OFF_QK + 0 * 256 + lane * 4);
    float4 qk1 = *(const float4*)(ws + OFF_QK + 1 * 256 + lane * 4);
    float4 qk2 = *(const float4*)(ws + OFF_QK + 2 * 256 + lane * 4);
    float4 qk3 = *(const float4*)(ws + OFF_QK + 3 * 256 + lane * 4);
    float4 qk4 = *(const float4*)(ws + OFF_QK + 4 * 256 + lane * 4);
    float4 qk5 = *(const float4*)(ws + OFF_QK + 5 * 256 + lane * 4);
    float4 qk6 = *(const float4*)(ws + OFF_QK + 6 * 256 + lane * 4);
    float4 qk7 = *(const float4*)(ws + OFF_QK + 7 * 256 + lane * 4);
    float qbreg = ws[OFF_QB + ep];

    // mask dtype detection (uniform)
    const int* mi = (const int*)mask;
    bool bytemode = __ballot((unsigned)mi[lane] > 1u) != 0ull;
    const unsigned char* mb_byte = mask + (long)b * L_;
    const int* mb_int = mi + (long)b * L_;

    float4 acc[8];
    #pragma unroll
    for (int h = 0; h < 8; ++h) acc[h] = make_float4(0.f, 0.f, 0.f, 0.f);
    float se = 0.f;  // lane (g,ep) accumulates sum of w[ep] (identical across g)

    int l0 = ch * CH + widx * WLEN;
    for (int w0 = l0; w0 < l0 + WLEN; w0 += 64) {
        int l = w0 + lane;
        bool valid = bytemode ? (mb_byte[l] != 0) : (mb_int[l] != 0);
        bool m = valid && (bb[l] == n);
        unsigned long long bal = __ballot(m);
        while (bal) {
            int i = __ffsll(bal) - 1;
            bal &= bal - 1;
            int tok = w0 + i;
            float4 xv = ((const float4*)(xb + (long)tok * D_))[lane];
            // per-lane partial dot for each head over this lane's 4 dims
            float p0 = xv.x * qk0.x + xv.y * qk0.y + xv.z * qk0.z + xv.w * qk0.w;
            float p1 = xv.x * qk1.x + xv.y * qk1.y + xv.z * qk1.z + xv.w * qk1.w;
            float p2 = xv.x * qk2.x + xv.y * qk2.y + xv.z * qk2.z + xv.w * qk2.w;
            float p3 = xv.x * qk3.x + xv.y * qk3.y + xv.z * qk3.z + xv.w * qk3.w;
            float p4 = xv.x * qk4.x + xv.y * qk4.y + xv.z * qk4.z + xv.w * qk4.w;
            float p5 = xv.x * qk5.x + xv.y * qk5.y + xv.z * qk5.z + xv.w * qk5.w;
            float p6 = xv.x * qk6.x + xv.y * qk6.y + xv.z * qk6.z + xv.w * qk6.w;
            float p7 = xv.x * qk7.x + xv.y * qk7.y + xv.z * qk7.z + xv.w * qk7.w;
            // butterfly: octet reduce (h spread over ep), then across octets
            float s = reduce_ep(p0, p1, p2, p3, p4, p5, p6, p7, ep);
            s += __shfl_xor(s, 8);
            s += __shfl_xor(s, 16);
            s += __shfl_xor(s, 32);
            float w = __expf(s + qbreg);   // lane ep holds w[ep]
            se += w;
            float wh0 = __shfl(w, 0), wh1 = __shfl(w, 1), wh2 = __shfl(w, 2), wh3 = __shfl(w, 3);
            float wh4 = __shfl(w, 4), wh5 = __shfl(w, 5), wh6 = __shfl(w, 6), wh7 = __shfl(w, 7);
            acc[0].x += wh0 * xv.x; acc[0].y += wh0 * xv.y; acc[0].z += wh0 * xv.z; acc[0].w += wh0 * xv.w;
            acc[1].x += wh1 * xv.x; acc[1].y += wh1 * xv.y; acc[1].z += wh1 * xv.z; acc[1].w += wh1 * xv.w;
            acc[2].x += wh2 * xv.x; acc[2].y += wh2 * xv.y; acc[2].z += wh2 * xv.z; acc[2].w += wh2 * xv.w;
            acc[3].x += wh3 * xv.x; acc[3].y += wh3 * xv.y; acc[3].z += wh3 * xv.z; acc[3].w += wh3 * xv.w;
            acc[4].x += wh4 * xv.x; acc[4].y += wh4 * xv.y; acc[4].z += wh4 * xv.z; acc[4].w += wh4 * xv.w;
            acc[5].x += wh5 * xv.x; acc[5].y += wh5 * xv.y; acc[5].z += wh5 * xv.z; acc[5].w += wh5 * xv.w;
            acc[6].x += wh6 * xv.x; acc[6].y += wh6 * xv.y; acc[6].z += wh6 * xv.z; acc[6].w += wh6 * xv.w;
            acc[7].x += wh7 * xv.x; acc[7].y += wh7 * xv.y; acc[7].z += wh7 * xv.z; acc[7].w += wh7 * xv.w;
        }
    }

    // cross-wave reduction in LDS
    #pragma unroll
    for (int h = 0; h < 8; ++h)
        *(float4*)(red + widx * 2048 + h * 256 + lane * 4) = acc[h];
    if (lane < 8) rse[widx * 8 + lane] = (lane == ep) ? se : __shfl(se, lane); // lane<8 => ep==lane
    __syncthreads();
    long base = (long)blk * 2048;
    for (int idx = t; idx < 2048; idx += 256) {
        float s = red[idx] + red[2048 + idx] + red[4096 + idx] + red[6144 + idx];
        part[base + idx] = s;
    }
    if (t < 8) pse[(long)blk * 8 + t] = rse[t] + rse[8 + t] + rse[16 + t] + rse[24 + t];
}

// ---------------------------------------------------------------- kernel 3
// One block per (n,b): reduce partials (fixed order), normalize, wv-project,
// out-project, LayerNorm, zero empty backends, write out[b][n][:].
template <int NCH>
__global__ __launch_bounds__(256) void k_epi(const float* __restrict__ part,
                                             const float* __restrict__ pse,
                                             const float* __restrict__ W,
                                             const float* __restrict__ ib,
                                             const float* __restrict__ Wo,
                                             const float* __restrict__ ob,
                                             const float* __restrict__ gamma,
                                             const float* __restrict__ beta,
                                             float* __restrict__ out) {
    __shared__ float pn[2048];
    __shared__ float ses[8];
    __shared__ float ctx_s[256];
    __shared__ float r1[4], r2[4];
    int n = blockIdx.x & 7, b = blockIdx.x >> 3;
    int t = threadIdx.x;
    int tbase = b * (NB_ * NCH) + n * NCH;
    if (t < 8) {
        float s = 0.f;
        for (int sub = 0; sub < NCH; ++sub) s += pse[(long)(tbase + sub) * 8 + t];
        ses[t] = s;
    }
    __syncthreads();
    bool has = ses[0] > 0.f;
    for (int j = 0; j < 8; ++j) {
        int idx = j * 256 + t;
        int h = idx >> 8;
        float s = 0.f;
        for (int sub = 0; sub < NCH; ++sub) s += part[(long)(tbase + sub) * 2048 + idx];
        pn[idx] = has ? s / ses[h] : 0.f;
    }
    __syncthreads();
    // ctx[t] = bv[t] + sum_e pn[h][e] * Wv[512+t][e]
    int h = t >> 5;
    float c = ib[512 + t];
    {
        const float* wr = W + (long)(512 + t) * 256;
        const float* ph = pn + h * 256;
        for (int e = 0; e < 256; e += 4) {
            float4 wv4 = *(const float4*)(wr + e);
            float4 pv4 = *(const float4*)(ph + e);
            c += wv4.x * pv4.x + wv4.y * pv4.y + wv4.z * pv4.z + wv4.w * pv4.w;
        }
    }
    ctx_s[t] = c;
    __syncthreads();
    float o = ob[t];
    {
        const float* wr = Wo + (long)t * 256;
        for (int d = 0; d < 256; d += 4) {
            float4 wv4 = *(const float4*)(wr + d);
            float4 cv4 = *(const float4*)(ctx_s + d);
            o += wv4.x * cv4.x + wv4.y * cv4.y + wv4.z * cv4.z + wv4.w * cv4.w;
        }
    }
    // LayerNorm over 256
    float s1 = o, s2 = o * o;
    #pragma unroll
    for (int off = 32; off >= 1; off >>= 1) {
        s1 += __shfl_down(s1, off);
        s2 += __shfl_down(s2, off);
    }
    if ((t & 63) == 0) { r1[t >> 6] = s1; r2[t >> 6] = s2; }
    __syncthreads();
    float S1 = r1[0] + r1[1] + r1[2] + r1[3];
    float S2 = r2[0] + r2[1] + r2[2] + r2[3];
    float mu = S1 * (1.f / 256.f);
    float var = S2 * (1.f / 256.f) - mu * mu;
    float rr = rsqrtf(var + 1e-5f);
    float res = ((o - mu) * rr * gamma[t] + beta[t]) * (has ? 1.f : 0.f);
    out[((long)b * 8 + n) * 256 + t] = res;
}

// ---------------------------------------------------------------- launch
extern "C" void kernel_launch(void* const* d_in, const int* in_sizes, int n_in,
                              void* d_out, int out_size, void* d_ws, size_t ws_size,
                              hipStream_t stream) {
    const float* x     = (const float*)d_in[0];
    const float* query = (const float*)d_in[1];
    const float* W     = (const float*)d_in[2];
    const float* ib    = (const float*)d_in[3];
    const float* Wo    = (const float*)d_in[4];
    const float* ob    = (const float*)d_in[5];
    const float* gamma = (const float*)d_in[6];
    const float* beta  = (const float*)d_in[7];
    const unsigned char* mask = (const unsigned char*)d_in[8];
    const int* bid     = (const int*)d_in[9];
    float* out = (float*)d_out;
    float* ws  = (float*)d_ws;

    k_setup<<<1, 256, 0, stream>>>(query, W, ib, ws);

    auto need = [](long nch) {
        return (size_t)(OFF_PART + (long)B_ * NB_ * nch * (2048 + 8)) * sizeof(float);
    };
    float* part = ws + OFF_PART;
    if (ws_size >= need(16)) {
        const int NCH = 16; // 2048 blocks, 8192 waves
        float* pse = part + (long)B_ * NB_ * NCH * 2048;
        k_pool<NCH><<<B_ * NB_ * NCH, 256, 0, stream>>>(x, mask, bid, ws, part, pse);
        k_epi<NCH><<<B_ * NB_, 256, 0, stream>>>(part, pse, W, ib, Wo, ob, gamma, beta, out);
    } else if (ws_size >= need(4)) {
        const int NCH = 4;
        float* pse = part + (long)B_ * NB_ * NCH * 2048;
        k_pool<NCH><<<B_ * NB_ * NCH, 256, 0, stream>>>(x, mask, bid, ws, part, pse);
        k_epi<NCH><<<B_ * NB_, 256, 0, stream>>>(part, pse, W, ib, Wo, ob, gamma, beta, out);
    } else {
        const int NCH = 1;
        float* pse = part + (long)B_ * NB_ * NCH * 2048;
        k_pool<NCH><<<B_ * NB_ * NCH, 256, 0, stream>>>(x, mask, bid, ws, part, pse);
        k_epi<NCH><<<B_ * NB_, 256, 0, stream>>>(part, pse, W, ib, Wo, ob, gamma, beta, out);
    }
}

// Round 4
// 68.388 us; speedup vs baseline: 1.8269x; 1.1424x over previous
//
#include <hip/hip_runtime.h>
#include <cstdint>
#include <cstddef>

#define B_  16
#define L_  8192
#define D_  256
#define H_  8
#define NB_ 8

// Workspace layout (floats): qk[8][256], qb[8], then partials + pse.
static const long OFF_QK   = 0;     // 8*256
static const long OFF_QB   = 2048;  // 8
static const long OFF_PART = 4096;  // part[task][8][256] then pse[task][8]

// ---------------------------------------------------------------- kernel 1
// 8 blocks, block h: qk[h][e] = (sum_d q[h*32+d] * Wk[256+h*32+d][e]) / sqrt(32).
__global__ __launch_bounds__(256) void k_setup(const float* __restrict__ query,
                                               const float* __restrict__ W,
                                               const float* __restrict__ bias,
                                               float* __restrict__ ws) {
    __shared__ float q_s[256];
    int t = threadIdx.x;
    int h = blockIdx.x;
    // Phase A (redundant per block, cheap): q projection row t.
    float acc = bias[t];
    const float* wr = W + (long)t * 256;
    #pragma unroll 8
    for (int e = 0; e < 256; e += 4) {
        float4 qv = *(const float4*)(query + e);
        float4 wv = *(const float4*)(wr + e);
        acc += qv.x * wv.x + qv.y * wv.y + qv.z * wv.z + qv.w * wv.w;
    }
    q_s[t] = acc;
    __syncthreads();
    const float rs = 0.17677669529663687f; // 1/sqrt(32)
    // Phase B: only this block's 32 rows of Wk.
    float s = 0.f;
    #pragma unroll 8
    for (int d = 0; d < 32; ++d) {
        int r = 256 + h * 32 + d;
        s += q_s[h * 32 + d] * W[(long)r * 256 + t];
    }
    ws[OFF_QK + h * 256 + t] = s * rs;
    if (t < 64) {
        float v = (t < 32) ? q_s[h * 32 + t] * bias[256 + h * 32 + t] : 0.f;
        v += __shfl_down(v, 16);
        v += __shfl_down(v, 8);
        v += __shfl_down(v, 4);
        v += __shfl_down(v, 2);
        v += __shfl_down(v, 1);
        if (t == 0) ws[OFF_QB + h] = v * rs;
    }
}

// 3-step butterfly over the low 3 lane bits: p0..p7 = per-lane partials for h=0..7.
// Result: lane (g,ep) holds sum over its 8-lane octet of p[ep].
__device__ __forceinline__ float reduce_ep(float p0, float p1, float p2, float p3,
                                           float p4, float p5, float p6, float p7, int ep) {
    bool b1 = (ep & 1) != 0;
    float s0 = b1 ? p0 : p1, k0 = b1 ? p1 : p0;
    float s1 = b1 ? p2 : p3, k1 = b1 ? p3 : p2;
    float s2 = b1 ? p4 : p5, k2 = b1 ? p5 : p4;
    float s3 = b1 ? p6 : p7, k3 = b1 ? p7 : p6;
    float n0 = k0 + __shfl_xor(s0, 1);
    float n1 = k1 + __shfl_xor(s1, 1);
    float n2 = k2 + __shfl_xor(s2, 1);
    float n3 = k3 + __shfl_xor(s3, 1);
    bool b2 = (ep & 2) != 0;
    float t0s = b2 ? n0 : n1, t0k = b2 ? n1 : n0;
    float t1s = b2 ? n2 : n3, t1k = b2 ? n3 : n2;
    float m0 = t0k + __shfl_xor(t0s, 2);
    float m1 = t1k + __shfl_xor(t1s, 2);
    bool b4 = (ep & 4) != 0;
    float us = b4 ? m0 : m1, uk = b4 ? m1 : m0;
    return uk + __shfl_xor(us, 4);
}

// ---------------------------------------------------------------- kernel 2 (fused scores+pool)
// One block per (b, n, chunk); 4 waves scan quarters. Ballot-screen, then gather
// matched rows TWO AT A TIME (independent chains -> ILP hides load+shfl latency).
// Scores computed in-register from the per-lane qk fragment; exp; weighted
// accumulate into register acc. Cross-wave LDS reduce -> one partial per block.
// No atomics; deterministic.
template <int NCH>
__global__ __launch_bounds__(256) void k_pool(const float* __restrict__ x,
                                              const unsigned char* __restrict__ mask,
                                              const int* __restrict__ bid,
                                              const float* __restrict__ ws,
                                              float* __restrict__ part,
                                              float* __restrict__ pse) {
    const int CH = L_ / NCH;      // tokens per block
    const int WLEN = CH / 4;      // tokens per wave
    __shared__ float red[4 * 2048];
    __shared__ float rse[4 * 8];

    int t = threadIdx.x;
    int widx = t >> 6, lane = t & 63;
    int ep = lane & 7;

    int blk = blockIdx.x;
    int b  = blk / (NB_ * NCH);
    int n  = (blk / NCH) % NB_;
    int ch = blk % NCH;

    const float* xb = x + (long)b * L_ * D_;
    const int*   bb = bid + (long)b * L_;

    // qk fragment for this lane: qk[h][lane*4 .. lane*4+4), h=0..7  (32 VGPR)
    float4 qk0 = *(const float4*)(ws + OFF_QK + 0 * 256 + lane * 4);
    float4 qk1 = *(const float4*)(ws + OFF_QK + 1 * 256 + lane * 4);
    float4 qk2 = *(const float4*)(ws + OFF_QK + 2 * 256 + lane * 4);
    float4 qk3 = *(const float4*)(ws + OFF_QK + 3 * 256 + lane * 4);
    float4 qk4 = *(const float4*)(ws + OFF_QK + 4 * 256 + lane * 4);
    float4 qk5 = *(const float4*)(ws + OFF_QK + 5 * 256 + lane * 4);
    float4 qk6 = *(const float4*)(ws + OFF_QK + 6 * 256 + lane * 4);
    float4 qk7 = *(const float4*)(ws + OFF_QK + 7 * 256 + lane * 4);
    float qbreg = ws[OFF_QB + ep];

    // mask dtype detection (uniform): packed 0/1 bytes read as int32 give a word
    // > 1 with probability 1 - 8^-64; a real int32 0/1 mask never does.
    const int* mi = (const int*)mask;
    bool bytemode = __ballot((unsigned)mi[lane] > 1u) != 0ull;
    const unsigned char* mb_byte = mask + (long)b * L_;
    const int* mb_int = mi + (long)b * L_;

    float4 acc[8];
    #pragma unroll
    for (int h = 0; h < 8; ++h) acc[h] = make_float4(0.f, 0.f, 0.f, 0.f);
    float se = 0.f;  // lane (g,ep): running sum of w[ep]

    int l0 = ch * CH + widx * WLEN;
    for (int w0 = l0; w0 < l0 + WLEN; w0 += 64) {
        int l = w0 + lane;
        bool valid = bytemode ? (mb_byte[l] != 0) : (mb_int[l] != 0);
        bool m = valid && (bb[l] == n);
        unsigned long long bal = __ballot(m);
        while (bal) {
            int i0 = __ffsll(bal) - 1; bal &= bal - 1;
            int i1 = -1;
            if (bal) { i1 = __ffsll(bal) - 1; bal &= bal - 1; }
            int tokA = w0 + i0;
            int tokB = w0 + (i1 >= 0 ? i1 : i0);
            float gB = (i1 >= 0) ? 1.f : 0.f;
            float4 xa = ((const float4*)(xb + (long)tokA * D_))[lane];
            float4 xc = ((const float4*)(xb + (long)tokB * D_))[lane];
            float pA0 = xa.x*qk0.x + xa.y*qk0.y + xa.z*qk0.z + xa.w*qk0.w;
            float pA1 = xa.x*qk1.x + xa.y*qk1.y + xa.z*qk1.z + xa.w*qk1.w;
            float pA2 = xa.x*qk2.x + xa.y*qk2.y + xa.z*qk2.z + xa.w*qk2.w;
            float pA3 = xa.x*qk3.x + xa.y*qk3.y + xa.z*qk3.z + xa.w*qk3.w;
            float pA4 = xa.x*qk4.x + xa.y*qk4.y + xa.z*qk4.z + xa.w*qk4.w;
            float pA5 = xa.x*qk5.x + xa.y*qk5.y + xa.z*qk5.z + xa.w*qk5.w;
            float pA6 = xa.x*qk6.x + xa.y*qk6.y + xa.z*qk6.z + xa.w*qk6.w;
            float pA7 = xa.x*qk7.x + xa.y*qk7.y + xa.z*qk7.z + xa.w*qk7.w;
            float pB0 = xc.x*qk0.x + xc.y*qk0.y + xc.z*qk0.z + xc.w*qk0.w;
            float pB1 = xc.x*qk1.x + xc.y*qk1.y + xc.z*qk1.z + xc.w*qk1.w;
            float pB2 = xc.x*qk2.x + xc.y*qk2.y + xc.z*qk2.z + xc.w*qk2.w;
            float pB3 = xc.x*qk3.x + xc.y*qk3.y + xc.z*qk3.z + xc.w*qk3.w;
            float pB4 = xc.x*qk4.x + xc.y*qk4.y + xc.z*qk4.z + xc.w*qk4.w;
            float pB5 = xc.x*qk5.x + xc.y*qk5.y + xc.z*qk5.z + xc.w*qk5.w;
            float pB6 = xc.x*qk6.x + xc.y*qk6.y + xc.z*qk6.z + xc.w*qk6.w;
            float pB7 = xc.x*qk7.x + xc.y*qk7.y + xc.z*qk7.z + xc.w*qk7.w;
            float sA = reduce_ep(pA0, pA1, pA2, pA3, pA4, pA5, pA6, pA7, ep);
            float sB = reduce_ep(pB0, pB1, pB2, pB3, pB4, pB5, pB6, pB7, ep);
            sA += __shfl_xor(sA, 8);  sB += __shfl_xor(sB, 8);
            sA += __shfl_xor(sA, 16); sB += __shfl_xor(sB, 16);
            sA += __shfl_xor(sA, 32); sB += __shfl_xor(sB, 32);
            float wA = __expf(sA + qbreg);
            float wB = __expf(sB + qbreg) * gB;
            se += wA + wB;
            {
                float a = __shfl(wA, 0), c = __shfl(wB, 0);
                acc[0].x += a*xa.x + c*xc.x; acc[0].y += a*xa.y + c*xc.y;
                acc[0].z += a*xa.z + c*xc.z; acc[0].w += a*xa.w + c*xc.w;
            }
            {
                float a = __shfl(wA, 1), c = __shfl(wB, 1);
                acc[1].x += a*xa.x + c*xc.x; acc[1].y += a*xa.y + c*xc.y;
                acc[1].z += a*xa.z + c*xc.z; acc[1].w += a*xa.w + c*xc.w;
            }
            {
                float a = __shfl(wA, 2), c = __shfl(wB, 2);
                acc[2].x += a*xa.x + c*xc.x; acc[2].y += a*xa.y + c*xc.y;
                acc[2].z += a*xa.z + c*xc.z; acc[2].w += a*xa.w + c*xc.w;
            }
            {
                float a = __shfl(wA, 3), c = __shfl(wB, 3);
                acc[3].x += a*xa.x + c*xc.x; acc[3].y += a*xa.y + c*xc.y;
                acc[3].z += a*xa.z + c*xc.z; acc[3].w += a*xa.w + c*xc.w;
            }
            {
                float a = __shfl(wA, 4), c = __shfl(wB, 4);
                acc[4].x += a*xa.x + c*xc.x; acc[4].y += a*xa.y + c*xc.y;
                acc[4].z += a*xa.z + c*xc.z; acc[4].w += a*xa.w + c*xc.w;
            }
            {
                float a = __shfl(wA, 5), c = __shfl(wB, 5);
                acc[5].x += a*xa.x + c*xc.x; acc[5].y += a*xa.y + c*xc.y;
                acc[5].z += a*xa.z + c*xc.z; acc[5].w += a*xa.w + c*xc.w;
            }
            {
                float a = __shfl(wA, 6), c = __shfl(wB, 6);
                acc[6].x += a*xa.x + c*xc.x; acc[6].y += a*xa.y + c*xc.y;
                acc[6].z += a*xa.z + c*xc.z; acc[6].w += a*xa.w + c*xc.w;
            }
            {
                float a = __shfl(wA, 7), c = __shfl(wB, 7);
                acc[7].x += a*xa.x + c*xc.x; acc[7].y += a*xa.y + c*xc.y;
                acc[7].z += a*xa.z + c*xc.z; acc[7].w += a*xa.w + c*xc.w;
            }
        }
    }

    // cross-wave reduction in LDS
    #pragma unroll
    for (int h = 0; h < 8; ++h)
        *(float4*)(red + widx * 2048 + h * 256 + lane * 4) = acc[h];
    if (lane < 8) rse[widx * 8 + lane] = se;  // lane<8 => ep==lane
    __syncthreads();
    long base = (long)blk * 2048;
    for (int idx = t; idx < 2048; idx += 256) {
        float s = red[idx] + red[2048 + idx] + red[4096 + idx] + red[6144 + idx];
        part[base + idx] = s;
    }
    if (t < 8) pse[(long)blk * 8 + t] = rse[t] + rse[8 + t] + rse[16 + t] + rse[24 + t];
}

// ---------------------------------------------------------------- kernel 3
// One block per (n,b): reduce partials (fixed order), normalize, wv-project,
// out-project, LayerNorm, zero empty backends, write out[b][n][:].
template <int NCH>
__global__ __launch_bounds__(256) void k_epi(const float* __restrict__ part,
                                             const float* __restrict__ pse,
                                             const float* __restrict__ W,
                                             const float* __restrict__ ib,
                                             const float* __restrict__ Wo,
                                             const float* __restrict__ ob,
                                             const float* __restrict__ gamma,
                                             const float* __restrict__ beta,
                                             float* __restrict__ out) {
    __shared__ float pn[2048];
    __shared__ float ses[8];
    __shared__ float ctx_s[256];
    __shared__ float r1[4], r2[4];
    int n = blockIdx.x & 7, b = blockIdx.x >> 3;
    int t = threadIdx.x;
    int tbase = b * (NB_ * NCH) + n * NCH;
    if (t < 8) {
        float s = 0.f;
        for (int sub = 0; sub < NCH; ++sub) s += pse[(long)(tbase + sub) * 8 + t];
        ses[t] = s;
    }
    __syncthreads();
    bool has = ses[0] > 0.f;
    for (int j = 0; j < 8; ++j) {
        int idx = j * 256 + t;
        int h = idx >> 8;
        float s = 0.f;
        for (int sub = 0; sub < NCH; ++sub) s += part[(long)(tbase + sub) * 2048 + idx];
        pn[idx] = has ? s / ses[h] : 0.f;
    }
    __syncthreads();
    // ctx[t] = bv[t] + sum_e pn[h][e] * Wv[512+t][e]
    int h = t >> 5;
    float c = ib[512 + t];
    {
        const float* wr = W + (long)(512 + t) * 256;
        const float* ph = pn + h * 256;
        for (int e = 0; e < 256; e += 4) {
            float4 wv4 = *(const float4*)(wr + e);
            float4 pv4 = *(const float4*)(ph + e);
            c += wv4.x * pv4.x + wv4.y * pv4.y + wv4.z * pv4.z + wv4.w * pv4.w;
        }
    }
    ctx_s[t] = c;
    __syncthreads();
    float o = ob[t];
    {
        const float* wr = Wo + (long)t * 256;
        for (int d = 0; d < 256; d += 4) {
            float4 wv4 = *(const float4*)(wr + d);
            float4 cv4 = *(const float4*)(ctx_s + d);
            o += wv4.x * cv4.x + wv4.y * cv4.y + wv4.z * cv4.z + wv4.w * cv4.w;
        }
    }
    // LayerNorm over 256
    float s1 = o, s2 = o * o;
    #pragma unroll
    for (int off = 32; off >= 1; off >>= 1) {
        s1 += __shfl_down(s1, off);
        s2 += __shfl_down(s2, off);
    }
    if ((t & 63) == 0) { r1[t >> 6] = s1; r2[t >> 6] = s2; }
    __syncthreads();
    float S1 = r1[0] + r1[1] + r1[2] + r1[3];
    float S2 = r2[0] + r2[1] + r2[2] + r2[3];
    float mu = S1 * (1.f / 256.f);
    float var = S2 * (1.f / 256.f) - mu * mu;
    float rr = rsqrtf(var + 1e-5f);
    float res = ((o - mu) * rr * gamma[t] + beta[t]) * (has ? 1.f : 0.f);
    out[((long)b * 8 + n) * 256 + t] = res;
}

// ---------------------------------------------------------------- launch
extern "C" void kernel_launch(void* const* d_in, const int* in_sizes, int n_in,
                              void* d_out, int out_size, void* d_ws, size_t ws_size,
                              hipStream_t stream) {
    const float* x     = (const float*)d_in[0];
    const float* query = (const float*)d_in[1];
    const float* W     = (const float*)d_in[2];
    const float* ib    = (const float*)d_in[3];
    const float* Wo    = (const float*)d_in[4];
    const float* ob    = (const float*)d_in[5];
    const float* gamma = (const float*)d_in[6];
    const float* beta  = (const float*)d_in[7];
    const unsigned char* mask = (const unsigned char*)d_in[8];
    const int* bid     = (const int*)d_in[9];
    float* out = (float*)d_out;
    float* ws  = (float*)d_ws;

    k_setup<<<8, 256, 0, stream>>>(query, W, ib, ws);

    auto need = [](long nch) {
        return (size_t)(OFF_PART + (long)B_ * NB_ * nch * (2048 + 8)) * sizeof(float);
    };
    float* part = ws + OFF_PART;
    if (ws_size >= need(16)) {
        const int NCH = 16; // 2048 blocks, 8192 waves
        float* pse = part + (long)B_ * NB_ * NCH * 2048;
        k_pool<NCH><<<B_ * NB_ * NCH, 256, 0, stream>>>(x, mask, bid, ws, part, pse);
        k_epi<NCH><<<B_ * NB_, 256, 0, stream>>>(part, pse, W, ib, Wo, ob, gamma, beta, out);
    } else if (ws_size >= need(4)) {
        const int NCH = 4;
        float* pse = part + (long)B_ * NB_ * NCH * 2048;
        k_pool<NCH><<<B_ * NB_ * NCH, 256, 0, stream>>>(x, mask, bid, ws, part, pse);
        k_epi<NCH><<<B_ * NB_, 256, 0, stream>>>(part, pse, W, ib, Wo, ob, gamma, beta, out);
    } else {
        const int NCH = 1;
        float* pse = part + (long)B_ * NB_ * NCH * 2048;
        k_pool<NCH><<<B_ * NB_ * NCH, 256, 0, stream>>>(x, mask, bid, ws, part, pse);
        k_epi<NCH><<<B_ * NB_, 256, 0, stream>>>(part, pse, W, ib, Wo, ob, gamma, beta, out);
    }
}